// Round 15
// baseline (133.488 us; speedup 1.0000x reference)
//
#include <hip/hip_runtime.h>

#define NCOMP 19
#define NB    4096

typedef float f32x2 __attribute__((ext_vector_type(2)));
typedef float f32x4 __attribute__((ext_vector_type(4)));

// ---- compile-time tables ----
constexpr float S20[21] = {
  0.0f, 0.15643446504023087f, 0.3090169943749474f, 0.45399049973954675f,
  0.5877852522924731f, 0.7071067811865476f, 0.8090169943749475f,
  0.8910065241883679f, 0.9510565162951535f, 0.9876883405951378f, 1.0f,
  0.9876883405951378f, 0.9510565162951535f, 0.8910065241883679f,
  0.8090169943749475f, 0.7071067811865476f, 0.5877852522924731f,
  0.45399049973954675f, 0.3090169943749474f, 0.15643446504023087f, 0.0f};

__host__ __device__ constexpr float sval(int m) {          // sin(m*pi/20)
  return (m <= 20) ? S20[m] : -S20[m - 20];
}
__host__ __device__ constexpr float vconst(int k, int j) { // V[k][j]
  return sval(((k + 1) * (j + 1)) % 40) * 0.31622776601683794f;
}

struct Tabs { float v[NCOMP][NCOMP]; float lam[NCOMP]; };
__host__ __device__ constexpr Tabs make_tabs() {
  Tabs T{};
  for (int k = 0; k < NCOMP; ++k) {
    for (int j = 0; j < NCOMP; ++j) T.v[k][j] = vconst(k, j);
    T.lam[k] = -2.0f * (1.0f - sval((k + 11) % 40));       // -4 sin^2((k+1)pi/40)
  }
  return T;
}
__constant__ Tabs VT = make_tabs();

// ---- DPP wave64 inclusive scan ----
template <int CTRL, int RMASK>
__device__ __forceinline__ float dpp_add(float x) {
  int v = __builtin_amdgcn_update_dpp(0, __float_as_int(x), CTRL, RMASK, 0xf, true);
  return x + __int_as_float(v);
}
__device__ __forceinline__ float wave_iscan(float x) {
  x = dpp_add<0x111, 0xf>(x);
  x = dpp_add<0x112, 0xf>(x);
  x = dpp_add<0x114, 0xf>(x);
  x = dpp_add<0x118, 0xf>(x);
  x = dpp_add<0x142, 0xa>(x);
  x = dpp_add<0x143, 0xc>(x);
  return x;
}

// LDS-ordering barrier WITHOUT vmcnt(0) drain: keeps global stores in flight.
__device__ __forceinline__ void lds_barrier() {
  asm volatile("s_waitcnt lgkmcnt(0)" ::: "memory");
  __builtin_amdgcn_s_barrier();
  __builtin_amdgcn_sched_barrier(0);
}

__device__ __forceinline__ float readlane_f(float v, int k) {
  return __int_as_float(__builtin_amdgcn_readlane(__float_as_int(v), k));
}

// 2048 persistent blocks x 4 (batch,system) pairs each; thread t owns steps
// 4t..4t+3 of the current pair. XCD-swizzled so each XCD writes one slab.
__global__ __launch_bounds__(256) void spm_fused(
    const float* __restrict__ xin, const float* __restrict__ iseq,
    const float* __restrict__ An, const float* __restrict__ Bn,
    const float* __restrict__ Ap, const float* __restrict__ Bp,
    float* __restrict__ out)
{
  __shared__ float4 mcv[2][NCOMP];                 // (gi, w*gi, log2 g, g)
  __shared__ float  mwv[2][NCOMP];                 // w
  __shared__ __align__(16) float wtot[2][NCOMP][4]; // parity-double-buffered

  const int t = threadIdx.x;
  const int lane = t & 63, wid = t >> 6;
  const int blk = blockIdx.x;
  const int swz = (blk & 7) * 256 + (blk >> 3);    // bijective, 2048 % 8 == 0
  const int pair0 = swz * 4;

  // one-time setup: modal constants for BOTH systems
  if (t < 2 * NCOMP) {
    int sy = t / NCOMP, k = t % NCOMP;
    float alpha = sy ? Ap[1] : An[1];
    float ab    = sy ? Bp[NCOMP - 1] : Bn[NCOMP - 1];
    float ha = 0.01f * alpha;
    float z  = ha * VT.lam[k];
    float g  = 1.0f + z * (1.0f + z * (0.5f + z * ((1.0f/6.0f) + z * (1.0f/24.0f))));
    float S  = 1.0f + z * (0.5f + z * ((1.0f/6.0f) + z * (1.0f/24.0f)));
    float gi = 1.0f / g;
    float w  = 0.01f * S * ab * VT.v[k][NCOMP - 1];
    mcv[sy][k] = make_float4(gi, w * gi, __builtin_log2f(g), g);
    mwv[sy][k] = w;
  }
  lds_barrier();

  const float pos = (float)(4 * t);

  for (int it = 0; it < 4; ++it) {
    const int pair = pair0 + it;
    const int b = pair >> 1, sys = pair & 1;
    const int par = it & 1;

    const float4 iv = *reinterpret_cast<const float4*>(iseq + (size_t)b * 1024 + t * 4);

    // per-wave s0: lanes 0..18 each compute one modal initial coordinate
    float s0v = 0.0f;
    if (lane < NCOMP) {
      const float* xr = xin + (size_t)b * (2 * NCOMP) + sys * NCOMP;
#pragma unroll
      for (int j = 0; j < NCOMP; ++j) s0v = fmaf(VT.v[lane][j], xr[j], s0v);
    }

    // Phase A: per-mode weighted wave-local scan (DPP)
    float Cp[NCOMP];
#pragma unroll
    for (int k = 0; k < NCOMP; ++k) {
      const float4 c = mcv[sys][k];
      float r = iv.x + c.x * (iv.y + c.x * (iv.z + c.x * iv.w));
      float a = __builtin_exp2f(-pos * c.z) * r;
      float v = wave_iscan(a);
      if (lane == 63) wtot[par][k][wid] = v;
      Cp[k] = v - a;
    }
    lds_barrier();   // orders wtot writes->reads; does NOT drain stores

    // Phase B: modal start + 4-step evolution, packed (t0,t1)/(t2,t3)
    f32x2 s01[NCOMP], s23[NCOMP];
#pragma unroll
    for (int k = 0; k < NCOMP; ++k) {
      const float4 c = mcv[sys][k];
      const float wk = mwv[sys][k];
      float4 q = *reinterpret_cast<const float4*>(&wtot[par][k][0]);
      float C = Cp[k];
      if (wid > 0) C += q.x;
      if (wid > 1) C += q.y;
      if (wid > 2) C += q.z;
      float s0k = readlane_f(s0v, k);
      float s  = __builtin_exp2f(pos * c.z) * fmaf(c.y, C, s0k);  // s_k(4t)
      float sA = fmaf(c.w, s,  wk * iv.x);
      float sB = fmaf(c.w, sA, wk * iv.y);
      float sC = fmaf(c.w, sB, wk * iv.z);
      float sD = fmaf(c.w, sC, wk * iv.w);
      s01[k] = (f32x2){sA, sB};
      s23[k] = (f32x2){sC, sD};
    }

    // Emit: parity-folded rows into registers, terminal nt-store burst
    f32x4 ob[NCOMP];
#pragma unroll
    for (int jj = 0; jj < 9; ++jj) {
      f32x2 E01 = {0.f, 0.f}, E23 = {0.f, 0.f};
      f32x2 O01 = {0.f, 0.f}, O23 = {0.f, 0.f};
#pragma unroll
      for (int k = 0; k < NCOMP; k += 2) {
        const f32x2 vk = { vconst(k, jj), vconst(k, jj) };
        E01 = __builtin_elementwise_fma(s01[k], vk, E01);
        E23 = __builtin_elementwise_fma(s23[k], vk, E23);
      }
#pragma unroll
      for (int k = 1; k < NCOMP; k += 2) {
        const f32x2 vk = { vconst(k, jj), vconst(k, jj) };
        O01 = __builtin_elementwise_fma(s01[k], vk, O01);
        O23 = __builtin_elementwise_fma(s23[k], vk, O23);
      }
      f32x2 p01 = E01 + O01, p23 = E23 + O23;
      f32x2 m01 = E01 - O01, m23 = E23 - O23;
      ob[jj]      = (f32x4){p01.x, p01.y, p23.x, p23.y};
      ob[18 - jj] = (f32x4){m01.x, m01.y, m23.x, m23.y};
    }
    {
      f32x2 E01 = {0.f, 0.f}, E23 = {0.f, 0.f};
#pragma unroll
      for (int k = 0; k < NCOMP; k += 2) {
        const f32x2 vk = { vconst(k, 9), vconst(k, 9) };
        E01 = __builtin_elementwise_fma(s01[k], vk, E01);
        E23 = __builtin_elementwise_fma(s23[k], vk, E23);
      }
      ob[9] = (f32x4){E01.x, E01.y, E23.x, E23.y};
    }

    float* orow = out + ((size_t)b * (2 * NCOMP) + sys * NCOMP) * 1024 + t * 4;
#pragma unroll
    for (int j = 0; j < NCOMP; ++j)
      __builtin_nontemporal_store(ob[j], reinterpret_cast<f32x4*>(orow + (size_t)j * 1024));
  }
}

extern "C" void kernel_launch(void* const* d_in, const int* in_sizes, int n_in,
                              void* d_out, int out_size, void* d_ws, size_t ws_size,
                              hipStream_t stream) {
  const float* x    = (const float*)d_in[0];
  const float* iseq = (const float*)d_in[1];
  const float* An   = (const float*)d_in[2];
  const float* Bn   = (const float*)d_in[3];
  const float* Ap   = (const float*)d_in[4];
  const float* Bp   = (const float*)d_in[5];
  float* out = (float*)d_out;

  spm_fused<<<2048, 256, 0, stream>>>(x, iseq, An, Bn, Ap, Bp, out);
}

// Round 16
// 127.611 us; speedup vs baseline: 1.0461x; 1.0461x over previous
//
#include <hip/hip_runtime.h>

#define NCOMP 19
#define NB    4096

typedef float f32x2 __attribute__((ext_vector_type(2)));
typedef float f32x4 __attribute__((ext_vector_type(4)));

// ---- compile-time tables ----
constexpr float S20[21] = {
  0.0f, 0.15643446504023087f, 0.3090169943749474f, 0.45399049973954675f,
  0.5877852522924731f, 0.7071067811865476f, 0.8090169943749475f,
  0.8910065241883679f, 0.9510565162951535f, 0.9876883405951378f, 1.0f,
  0.9876883405951378f, 0.9510565162951535f, 0.8910065241883679f,
  0.8090169943749475f, 0.7071067811865476f, 0.5877852522924731f,
  0.45399049973954675f, 0.3090169943749474f, 0.15643446504023087f, 0.0f};

__host__ __device__ constexpr float sval(int m) {          // sin(m*pi/20)
  return (m <= 20) ? S20[m] : -S20[m - 20];
}
__host__ __device__ constexpr float vconst(int k, int j) { // V[k][j]
  return sval(((k + 1) * (j + 1)) % 40) * 0.31622776601683794f;
}

struct Tabs { float v[NCOMP][NCOMP]; float lam[NCOMP]; };
__host__ __device__ constexpr Tabs make_tabs() {
  Tabs T{};
  for (int k = 0; k < NCOMP; ++k) {
    for (int j = 0; j < NCOMP; ++j) T.v[k][j] = vconst(k, j);
    T.lam[k] = -2.0f * (1.0f - sval((k + 11) % 40));       // -4 sin^2((k+1)pi/40)
  }
  return T;
}
__constant__ Tabs VT = make_tabs();

// ---- DPP wave64 inclusive scan ----
template <int CTRL, int RMASK>
__device__ __forceinline__ float dpp_add(float x) {
  int v = __builtin_amdgcn_update_dpp(0, __float_as_int(x), CTRL, RMASK, 0xf, true);
  return x + __int_as_float(v);
}
__device__ __forceinline__ float wave_iscan(float x) {
  x = dpp_add<0x111, 0xf>(x);
  x = dpp_add<0x112, 0xf>(x);
  x = dpp_add<0x114, 0xf>(x);
  x = dpp_add<0x118, 0xf>(x);
  x = dpp_add<0x142, 0xa>(x);
  x = dpp_add<0x143, 0xc>(x);
  return x;
}

// one block (4 waves) = one (batch, system); thread t owns steps 4t..4t+3.
__global__ __launch_bounds__(256) void spm_fused(
    const float* __restrict__ xin, const float* __restrict__ iseq,
    const float* __restrict__ An, const float* __restrict__ Bn,
    const float* __restrict__ Ap, const float* __restrict__ Bp,
    float* __restrict__ out)
{
  __shared__ float xs0[NCOMP];
  __shared__ float4 mcv[NCOMP];                   // (gi, w*gi, log2 g, s0)
  __shared__ float2 mgw[NCOMP];                   // (g, w)
  __shared__ __align__(16) float wtot[NCOMP][4];

  const int t = threadIdx.x;
  const int lane = t & 63, wid = t >> 6;
  const int b = blockIdx.x >> 1, sys = blockIdx.x & 1;
  const float alpha = sys ? Ap[1] : An[1];
  const float ha    = 0.01f * alpha;

  // issue input load early
  const float4 iv = *reinterpret_cast<const float4*>(iseq + (size_t)b * 1024 + t * 4);

  if (t < NCOMP) xs0[t] = xin[(size_t)b * (2 * NCOMP) + sys * NCOMP + t];
  __syncthreads();

  if (t < NCOMP) {
    float ab = sys ? Bp[NCOMP - 1] : Bn[NCOMP - 1];
    float z  = ha * VT.lam[t];
    float g  = 1.0f + z * (1.0f + z * (0.5f + z * ((1.0f/6.0f) + z * (1.0f/24.0f))));
    float S  = 1.0f + z * (0.5f + z * ((1.0f/6.0f) + z * (1.0f/24.0f)));
    float gi = 1.0f / g;
    float w  = 0.01f * S * ab * VT.v[t][NCOMP - 1];        // modal input weight
    float s0 = 0.0f;
#pragma unroll
    for (int j = 0; j < NCOMP; ++j) s0 = fmaf(VT.v[t][j], xs0[j], s0);
    mcv[t] = make_float4(gi, w * gi, __builtin_log2f(g), s0);
    mgw[t] = make_float2(g, w);
  }
  __syncthreads();

  const float pos = (float)(4 * t);

  // Phase A: per-mode weighted wave-local scan (DPP)
  float Cp[NCOMP];
#pragma unroll
  for (int k = 0; k < NCOMP; ++k) {
    const float4 c = mcv[k];
    float r = iv.x + c.x * (iv.y + c.x * (iv.z + c.x * iv.w));
    float a = __builtin_exp2f(-pos * c.z) * r;
    float v = wave_iscan(a);
    if (lane == 63) wtot[k][wid] = v;
    Cp[k] = v - a;
  }
  __syncthreads();

  // Phase B: modal start state + 4-step modal evolution, packed (t0,t1)/(t2,t3)
  f32x2 s01[NCOMP], s23[NCOMP];
#pragma unroll
  for (int k = 0; k < NCOMP; ++k) {
    const float4 c = mcv[k];
    const float2 gw = mgw[k];
    float4 q = *reinterpret_cast<const float4*>(&wtot[k][0]);
    float C = Cp[k];
    if (wid > 0) C += q.x;
    if (wid > 1) C += q.y;
    if (wid > 2) C += q.z;
    float s  = __builtin_exp2f(pos * c.z) * fmaf(c.y, C, c.w);  // s_k(4t)
    float sA = fmaf(gw.x, s,  gw.y * iv.x);
    float sB = fmaf(gw.x, sA, gw.y * iv.y);
    float sC = fmaf(gw.x, sB, gw.y * iv.z);
    float sD = fmaf(gw.x, sC, gw.y * iv.w);
    s01[k] = (f32x2){sA, sB};
    s23[k] = (f32x2){sC, sD};
  }

  // Emit: parity-folded rows into registers (packed fma), then terminal burst.
  f32x4 ob[NCOMP];
#pragma unroll
  for (int jj = 0; jj < 9; ++jj) {
    f32x2 E01 = {0.f, 0.f}, E23 = {0.f, 0.f};
    f32x2 O01 = {0.f, 0.f}, O23 = {0.f, 0.f};
#pragma unroll
    for (int k = 0; k < NCOMP; k += 2) {          // even modes: symmetric
      const f32x2 vk = { vconst(k, jj), vconst(k, jj) };
      E01 = __builtin_elementwise_fma(s01[k], vk, E01);
      E23 = __builtin_elementwise_fma(s23[k], vk, E23);
    }
#pragma unroll
    for (int k = 1; k < NCOMP; k += 2) {          // odd modes: antisymmetric
      const f32x2 vk = { vconst(k, jj), vconst(k, jj) };
      O01 = __builtin_elementwise_fma(s01[k], vk, O01);
      O23 = __builtin_elementwise_fma(s23[k], vk, O23);
    }
    f32x2 p01 = E01 + O01, p23 = E23 + O23;
    f32x2 m01 = E01 - O01, m23 = E23 - O23;
    ob[jj]      = (f32x4){p01.x, p01.y, p23.x, p23.y};
    ob[18 - jj] = (f32x4){m01.x, m01.y, m23.x, m23.y};
  }
  {   // center row j=9: odd modes vanish
    f32x2 E01 = {0.f, 0.f}, E23 = {0.f, 0.f};
#pragma unroll
    for (int k = 0; k < NCOMP; k += 2) {
      const f32x2 vk = { vconst(k, 9), vconst(k, 9) };
      E01 = __builtin_elementwise_fma(s01[k], vk, E01);
      E23 = __builtin_elementwise_fma(s23[k], vk, E23);
    }
    ob[9] = (f32x4){E01.x, E01.y, E23.x, E23.y};
  }

  float* orow = out + ((size_t)b * (2 * NCOMP) + sys * NCOMP) * 1024 + t * 4;
#pragma unroll
  for (int j = 0; j < NCOMP; ++j)
    __builtin_nontemporal_store(ob[j], reinterpret_cast<f32x4*>(orow + (size_t)j * 1024));
}

extern "C" void kernel_launch(void* const* d_in, const int* in_sizes, int n_in,
                              void* d_out, int out_size, void* d_ws, size_t ws_size,
                              hipStream_t stream) {
  const float* x    = (const float*)d_in[0];
  const float* iseq = (const float*)d_in[1];
  const float* An   = (const float*)d_in[2];
  const float* Bn   = (const float*)d_in[3];
  const float* Ap   = (const float*)d_in[4];
  const float* Bp   = (const float*)d_in[5];
  float* out = (float*)d_out;

  spm_fused<<<NB * 2, 256, 0, stream>>>(x, iseq, An, Bn, Ap, Bp, out);
}